// Round 12
// baseline (229.049 us; speedup 1.0000x reference)
//
#include <hip/hip_runtime.h>

#define LORA_RANK 16
#define SCALING 2.0f

using bf16x8 = __attribute__((ext_vector_type(8))) __bf16;
using bf16x4 = __attribute__((ext_vector_type(4))) __bf16;
using f32x4  = __attribute__((ext_vector_type(4))) float;
using i32x4  = __attribute__((ext_vector_type(4))) int;

#define GLB(p) ((const __attribute__((address_space(1))) void*)(p))
#define LDS(p) ((__attribute__((address_space(3))) void*)(p))

// ---------------------------------------------------------------------------
// L[o][i] = SCALING * sum_r lB[o][r]*lA[r][i]  -> bf16 into d_ws scratch.
// ---------------------------------------------------------------------------
__global__ __launch_bounds__(256) void lora_mat_kernel(
    const float* __restrict__ lA, const float* __restrict__ lB,
    __bf16* __restrict__ L, int N, int K)
{
    const int i0 = blockIdx.x * 256;
    const int o0 = blockIdx.y * 64;
    const int t  = threadIdx.x;

    __shared__ float As[LORA_RANK][256];
    __shared__ float Bs[64][LORA_RANK];

    #pragma unroll
    for (int j = 0; j < 16; ++j) {
        int idx = t + j * 256;
        int r = idx >> 8, c = idx & 255;
        As[r][c] = lA[(long)r * K + i0 + c];
    }
    #pragma unroll
    for (int j = 0; j < 4; ++j) {
        int idx = t + j * 256;
        int o = idx >> 4, r = idx & 15;
        Bs[o][r] = lB[(long)(o0 + o) * LORA_RANK + r] * SCALING;
    }
    __syncthreads();

    const int ol = t & 63;
    const int iq = t >> 6;
    const int o  = o0 + ol;

    float bb[LORA_RANK];
    #pragma unroll
    for (int r = 0; r < LORA_RANK; ++r) bb[r] = Bs[ol][r];

    __bf16* lrow = L + (long)o * K + i0 + iq * 64;
    #pragma unroll
    for (int c = 0; c < 16; ++c) {
        const int ib = iq * 64 + c * 4;
        f32x4 v = {0.f, 0.f, 0.f, 0.f};
        #pragma unroll
        for (int r = 0; r < LORA_RANK; ++r) {
            v[0] += bb[r] * As[r][ib + 0];
            v[1] += bb[r] * As[r][ib + 1];
            v[2] += bb[r] * As[r][ib + 2];
            v[3] += bb[r] * As[r][ib + 3];
        }
        bf16x4 wv;
        wv[0] = (__bf16)v[0]; wv[1] = (__bf16)v[1];
        wv[2] = (__bf16)v[2]; wv[3] = (__bf16)v[3];
        *(bf16x4*)(lrow + c * 4) = wv;
    }
}

// ---------------------------------------------------------------------------
// Per-output-row: W' = q*s + L; s' = rowmax/127; W8 = round(W'/s').  K==4096.
// ---------------------------------------------------------------------------
__global__ __launch_bounds__(256) void quant_w_kernel(
    const int* __restrict__ q, const float* __restrict__ scales,
    const __bf16* __restrict__ L, signed char* __restrict__ W8,
    float* __restrict__ sn, int K)
{
    const int o = blockIdx.x, t = threadIdx.x;
    __shared__ float buf[4096];
    __shared__ float red[256];

    const int4*   qr = (const int4*)(q + (long)o * K);
    const bf16x4* Lr = (const bf16x4*)(L + (long)o * K);
    const float   s  = scales[o];

    float mx = 0.f;
    #pragma unroll
    for (int j = 0; j < 4; ++j) {
        int c = t + j * 256;
        int4   qv = qr[c];
        bf16x4 lv = Lr[c];
        f32x4 w;
        w[0] = (float)qv.x * s + (float)lv[0];
        w[1] = (float)qv.y * s + (float)lv[1];
        w[2] = (float)qv.z * s + (float)lv[2];
        w[3] = (float)qv.w * s + (float)lv[3];
        *(f32x4*)&buf[c * 4] = w;
        mx = fmaxf(mx, fmaxf(fmaxf(fabsf(w[0]), fabsf(w[1])),
                             fmaxf(fabsf(w[2]), fabsf(w[3]))));
    }
    red[t] = mx;
    __syncthreads();
    for (int s2 = 128; s2 > 0; s2 >>= 1) {
        if (t < s2) red[t] = fmaxf(red[t], red[t + s2]);
        __syncthreads();
    }
    const float gmax = fmaxf(red[0], 1e-30f);
    const float winv = 127.0f / gmax;

    int* wrow = (int*)(W8 + (long)o * K);
    #pragma unroll
    for (int j = 0; j < 4; ++j) {
        int c = t + j * 256;
        f32x4 w = *(const f32x4*)&buf[c * 4];
        int c0 = (int)rintf(fminf(fmaxf(w[0] * winv, -127.f), 127.f));
        int c1 = (int)rintf(fminf(fmaxf(w[1] * winv, -127.f), 127.f));
        int c2 = (int)rintf(fminf(fmaxf(w[2] * winv, -127.f), 127.f));
        int c3 = (int)rintf(fminf(fmaxf(w[3] * winv, -127.f), 127.f));
        wrow[c] = (c0 & 255) | ((c1 & 255) << 8) | ((c2 & 255) << 16) | (c3 << 24);
    }
    if (t == 0) sn[o] = gmax / 127.0f;
}

// ---------------------------------------------------------------------------
// Per-X-row: sx = rowmax|x|/127; X8 = round(x/sx).  K==4096.
// ---------------------------------------------------------------------------
__global__ __launch_bounds__(256) void quant_x_kernel(
    const float* __restrict__ X, signed char* __restrict__ X8,
    float* __restrict__ sxm, int K)
{
    const int m = blockIdx.x, t = threadIdx.x;
    __shared__ float red[256];

    const f32x4* xr = (const f32x4*)(X + (long)m * K);
    f32x4 v[4];
    float mx = 0.f;
    #pragma unroll
    for (int j = 0; j < 4; ++j) {
        v[j] = xr[t + j * 256];
        mx = fmaxf(mx, fmaxf(fmaxf(fabsf(v[j][0]), fabsf(v[j][1])),
                             fmaxf(fabsf(v[j][2]), fabsf(v[j][3]))));
    }
    red[t] = mx;
    __syncthreads();
    for (int s2 = 128; s2 > 0; s2 >>= 1) {
        if (t < s2) red[t] = fmaxf(red[t], red[t + s2]);
        __syncthreads();
    }
    const float gmax = fmaxf(red[0], 1e-30f);
    const float xinv = 127.0f / gmax;

    int* xrow = (int*)(X8 + (long)m * K);
    #pragma unroll
    for (int j = 0; j < 4; ++j) {
        int c0 = (int)rintf(fminf(fmaxf(v[j][0] * xinv, -127.f), 127.f));
        int c1 = (int)rintf(fminf(fmaxf(v[j][1] * xinv, -127.f), 127.f));
        int c2 = (int)rintf(fminf(fmaxf(v[j][2] * xinv, -127.f), 127.f));
        int c3 = (int)rintf(fminf(fmaxf(v[j][3] * xinv, -127.f), 127.f));
        xrow[t + j * 256] = (c0 & 255) | ((c1 & 255) << 8) | ((c2 & 255) << 16) | (c3 << 24);
    }
    if (t == 0) sxm[m] = gmax / 127.0f;
}

// ---------------------------------------------------------------------------
// INT8 GEMM: 256x128 block tile, BK=128, 128B rows + 8-chunk XOR swizzle
// (verified conflict-free). Register-level slice pipeline: two explicit
// fragment sets; each step issues {reads(slice s+1) -> other set} with NO
// wait before {MFMAs(slice s)} -> LDS port and MFMA pipe overlap.
// 8 waves (4M x 2N), per-wave 64x64 out. 1 barrier+1 vmcnt+1 lgkm per K-tile.
// ---------------------------------------------------------------------------
#define VMW0  asm volatile("s_waitcnt vmcnt(0)" ::: "memory")
#define VMW6  asm volatile("s_waitcnt vmcnt(6)" ::: "memory")
#define LGKM0 asm volatile("s_waitcnt lgkmcnt(0)" ::: "memory")

#define RD4(base, off) (*(const i32x4*)((base) + (off)))

#define MFI(mi, nj, A, B) \
    acc[mi][nj] = __builtin_amdgcn_mfma_i32_16x16x64_i8(A, B, acc[mi][nj], 0, 0, 0)

#define DECLF(p) i32x4 p##a0, p##a1, p##a2, p##a3, p##b0, p##b1, p##b2, p##b3

#define READF(p, ac, bc, kc) do { \
    p##b0 = RD4(bc, bRow +    0 + (kc)); \
    p##b1 = RD4(bc, bRow + 2048 + (kc)); \
    p##b2 = RD4(bc, bRow + 4096 + (kc)); \
    p##b3 = RD4(bc, bRow + 6144 + (kc)); \
    p##a0 = RD4(ac, aRow +    0 + (kc)); \
    p##a1 = RD4(ac, aRow + 2048 + (kc)); \
    p##a2 = RD4(ac, aRow + 4096 + (kc)); \
    p##a3 = RD4(ac, aRow + 6144 + (kc)); } while (0)

#define MFMAS(p) do { \
    __builtin_amdgcn_s_setprio(1); \
    MFI(0,0,p##a0,p##b0); MFI(1,0,p##a1,p##b0); MFI(2,0,p##a2,p##b0); MFI(3,0,p##a3,p##b0); \
    MFI(0,1,p##a0,p##b1); MFI(1,1,p##a1,p##b1); MFI(2,1,p##a2,p##b1); MFI(3,1,p##a3,p##b1); \
    MFI(0,2,p##a0,p##b2); MFI(1,2,p##a1,p##b2); MFI(2,2,p##a2,p##b2); MFI(3,2,p##a3,p##b2); \
    MFI(0,3,p##a0,p##b3); MFI(1,3,p##a1,p##b3); MFI(2,3,p##a2,p##b3); MFI(3,3,p##a3,p##b3); \
    __builtin_amdgcn_s_setprio(0); } while (0)

// stage A (256x128B, 4 rounds) + B (128x128B, 2 rounds); 6 DMA / thread
#define STAGE6(dA, dB) do { \
    __builtin_amdgcn_global_load_lds(GLB(pA),          LDS((dA) + wb),         16, 0, 0); \
    __builtin_amdgcn_global_load_lds(GLB(pA + rk),     LDS((dA) + wb +  8192), 16, 0, 0); \
    __builtin_amdgcn_global_load_lds(GLB(pA + 2 * rk), LDS((dA) + wb + 16384), 16, 0, 0); \
    __builtin_amdgcn_global_load_lds(GLB(pA + 3 * rk), LDS((dA) + wb + 24576), 16, 0, 0); \
    __builtin_amdgcn_global_load_lds(GLB(pB),          LDS((dB) + wb),         16, 0, 0); \
    __builtin_amdgcn_global_load_lds(GLB(pB + rk),     LDS((dB) + wb +  8192), 16, 0, 0); } while (0)

#define ADVP8(a) do { pA += (a); pB += (a); } while (0)

__global__ __launch_bounds__(512, 2) void gemm_i8_kernel(
    const signed char* __restrict__ X8, const signed char* __restrict__ W8,
    const float* __restrict__ sxm, const float* __restrict__ sn,
    const float* __restrict__ bias, float* __restrict__ C,
    int M, int N, int K)
{
    // bA0 [0,32K) bB0 [32K,48K) bA1 [48K,80K) bB1 [80K,96K)
    __shared__ __align__(16) char smem[98304];

    const int t = threadIdx.x, wid = t >> 6, lane = t & 63;
    const int wr = wid >> 1, wc = wid & 1;
    const int l15 = lane & 15, l7 = lane & 7, lk = lane >> 4;

    const int nwg = gridDim.x;
    int bid = blockIdx.x;
    if ((nwg & 7) == 0) bid = (bid & 7) * (nwg >> 3) + (bid >> 3);
    const int ntn = N >> 7;
    const int m0 = (bid / ntn) << 8, n0 = (bid % ntn) << 7;

    // staging: thread t sources row (t>>3)(+64k), chunk (t&7)^((t>>3)&7)
    const int sr = t >> 3;
    const int ch = (t & 7) ^ (sr & 7);
    const long rk = 64L * K;
    const signed char* pA = X8 + (long)(m0 + sr) * K + ch * 16;
    const signed char* pB = W8 + (long)(n0 + sr) * K + ch * 16;

    const int wb = wid * 1024;                     // wave-uniform stage base

    // fragment reads: row base+l15 (+16*i), k-chunk (lk + 4*ks) ^ (row&7)
    const int aRow = (wr * 64 + l15) * 128;
    const int bRow = (wc * 64 + l15) * 128;
    const int kc0  = ((lk    ) ^ l7) << 4;
    const int kc1  = ((lk + 4) ^ l7) << 4;

    char* const bA0 = smem;
    char* const bB0 = smem + 32768;
    char* const bA1 = smem + 49152;
    char* const bB1 = smem + 81920;

    i32x4 acc[4][4] = {};

    const int nkt = K >> 7;                        // BK = 128 (nkt even, >=2)

    // prologue: stage t0 and t1, wait t0, read s0(t0)
    STAGE6(bA0, bB0);
    ADVP8(nkt > 1 ? 128 : 0);
    STAGE6(bA1, bB1);
    ADVP8(nkt > 2 ? 128 : 0);
    VMW6;                                          // t0's 6 DMAs done
    __builtin_amdgcn_s_barrier();

    DECLF(x);
    DECLF(y);
    READF(x, bA0, bB0, kc0);                       // s0(t0)

    for (int kt = 0; kt < nkt; kt += 2) {
        // ---- tile kt (buffers 0) ----
        READF(y, bA0, bB0, kc1);                   // s1(kt)  (no wait before MFMAs)
        MFMAS(x);                                  // s0(kt)
        LGKM0; VMW0;                               // my reads returned; DMA(kt+1) done
        __builtin_amdgcn_s_barrier();
        STAGE6(bA0, bB0);                          // stage kt+2 over buf0
        ADVP8((kt + 3 < nkt) ? 128 : 0);
        READF(x, bA1, bB1, kc0);                   // s0(kt+1)
        MFMAS(y);                                  // s1(kt)
        // ---- tile kt+1 (buffers 1) ----
        READF(y, bA1, bB1, kc1);                   // s1(kt+1)
        MFMAS(x);                                  // s0(kt+1)
        LGKM0; VMW0;                               // DMA(kt+2) done
        __builtin_amdgcn_s_barrier();
        STAGE6(bA1, bB1);                          // stage kt+3 over buf1
        ADVP8((kt + 4 < nkt) ? 128 : 0);
        READF(x, bA0, bB0, kc0);                   // s0(kt+2)
        MFMAS(y);                                  // s1(kt+1)
    }

    // epilogue: col = lane&15 (+nj*16), row = (lane>>4)*4 + e (+mi*16)
    #pragma unroll
    for (int nj = 0; nj < 4; ++nj) {
        const int col = n0 + wc * 64 + nj * 16 + l15;
        const float scol = sn[col];
        const float bv   = bias[col];
        #pragma unroll
        for (int mi = 0; mi < 4; ++mi) {
            const long rowb = (long)m0 + wr * 64 + mi * 16 + (lane >> 4) * 4;
            const f32x4 sx4 = *(const f32x4*)(sxm + rowb);
            float* Cp = C + rowb * N + col;
            Cp[0]       = (float)acc[mi][nj][0] * (sx4[0] * scol) + bv;
            Cp[(long)N] = (float)acc[mi][nj][1] * (sx4[1] * scol) + bv;
            Cp[2L * N]  = (float)acc[mi][nj][2] * (sx4[2] * scol) + bv;
            Cp[3L * N]  = (float)acc[mi][nj][3] * (sx4[3] * scol) + bv;
        }
    }
}

// ---------------------------------------------------------------------------
// bf16 fallback path for unexpected shapes.
// ---------------------------------------------------------------------------
__global__ __launch_bounds__(256) void fold_weight_kernel(
    const int* __restrict__ q, const float* __restrict__ scales,
    const float* __restrict__ lA, const float* __restrict__ lB,
    __bf16* __restrict__ W, int N, int K)
{
    const int i0 = blockIdx.x * 256;
    const int o0 = blockIdx.y * 64;
    const int t  = threadIdx.x;

    __shared__ float As[LORA_RANK][256];
    __shared__ float Bs[64][LORA_RANK];

    #pragma unroll
    for (int j = 0; j < 16; ++j) {
        int idx = t + j * 256;
        As[idx >> 8][idx & 255] = lA[(long)(idx >> 8) * K + i0 + (idx & 255)];
    }
    #pragma unroll
    for (int j = 0; j < 4; ++j) {
        int idx = t + j * 256;
        Bs[idx >> 4][idx & 15] = lB[(long)(o0 + (idx >> 4)) * LORA_RANK + (idx & 15)] * SCALING;
    }
    __syncthreads();

    const int ol = t & 63, iq = t >> 6, o = o0 + ol;
    const float sc = scales[o];
    float bb[LORA_RANK];
    #pragma unroll
    for (int r = 0; r < LORA_RANK; ++r) bb[r] = Bs[ol][r];

    const int* qrow = q + (long)o * K + i0 + iq * 64;
    __bf16*    wrow = W + (long)o * K + i0 + iq * 64;
    #pragma unroll
    for (int c = 0; c < 16; ++c) {
        int4 q4 = *(const int4*)(qrow + c * 4);
        float v[4] = {(float)q4.x * sc, (float)q4.y * sc, (float)q4.z * sc, (float)q4.w * sc};
        const int ib = iq * 64 + c * 4;
        #pragma unroll
        for (int r = 0; r < LORA_RANK; ++r) {
            v[0] += bb[r] * As[r][ib + 0]; v[1] += bb[r] * As[r][ib + 1];
            v[2] += bb[r] * As[r][ib + 2]; v[3] += bb[r] * As[r][ib + 3];
        }
        bf16x4 wv; wv[0] = (__bf16)v[0]; wv[1] = (__bf16)v[1];
        wv[2] = (__bf16)v[2]; wv[3] = (__bf16)v[3];
        *(bf16x4*)(wrow + c * 4) = wv;
    }
}

__global__ __launch_bounds__(256) void cvt_x_kernel(
    const float* __restrict__ X, __bf16* __restrict__ Xb, long n)
{
    const long stride = (long)gridDim.x * 256 * 8;
    for (long i = ((long)blockIdx.x * 256 + threadIdx.x) * 8; i < n; i += stride) {
        f32x4 a = *(const f32x4*)(X + i);
        f32x4 b = *(const f32x4*)(X + i + 4);
        bf16x8 v;
        #pragma unroll
        for (int j = 0; j < 4; ++j) { v[j] = (__bf16)a[j]; v[j + 4] = (__bf16)b[j]; }
        *(bf16x8*)(Xb + i) = v;
    }
}

#define RD8(base, off) (*(const bf16x8*)((base) + (off)))
#define MF(mi, nj, A, B) \
    acc[mi][nj] = __builtin_amdgcn_mfma_f32_16x16x32_bf16(A, B, acc[mi][nj], 0, 0, 0)
#define SWEEP16(qb, A0, A1, A2, A3, B0, B1, B2, B3) \
    MF((qb)+0,0,A0,B0); MF((qb)+1,0,A1,B0); MF((qb)+2,0,A2,B0); MF((qb)+3,0,A3,B0); \
    MF((qb)+0,1,A0,B1); MF((qb)+1,1,A1,B1); MF((qb)+2,1,A2,B1); MF((qb)+3,1,A3,B1); \
    MF((qb)+0,2,A0,B2); MF((qb)+1,2,A1,B2); MF((qb)+2,2,A2,B2); MF((qb)+3,2,A3,B2); \
    MF((qb)+0,3,A0,B3); MF((qb)+1,3,A1,B3); MF((qb)+2,3,A2,B3); MF((qb)+3,3,A3,B3);
#define STAGE_ALL(dA, dB) do { \
    __builtin_amdgcn_global_load_lds(GLB(pB0),  LDS((dB) + wb),         16, 0, 0); \
    __builtin_amdgcn_global_load_lds(GLB(pB0b), LDS((dB) + wb +  8192), 16, 0, 0); \
    __builtin_amdgcn_global_load_lds(GLB(pB1),  LDS((dB) + wb + 16384), 16, 0, 0); \
    __builtin_amdgcn_global_load_lds(GLB(pB1b), LDS((dB) + wb + 24576), 16, 0, 0); \
    __builtin_amdgcn_global_load_lds(GLB(pA0),  LDS((dA) + wb),         16, 0, 0); \
    __builtin_amdgcn_global_load_lds(GLB(pA0b), LDS((dA) + wb +  8192), 16, 0, 0); \
    __builtin_amdgcn_global_load_lds(GLB(pA1),  LDS((dA) + wb + 16384), 16, 0, 0); \
    __builtin_amdgcn_global_load_lds(GLB(pA1b), LDS((dA) + wb + 24576), 16, 0, 0); } while (0)
#define ADVP(a) do { pA0 += (a); pA0b += (a); pA1 += (a); pA1b += (a); \
                     pB0 += (a); pB0b += (a); pB1 += (a); pB1b += (a); } while (0)
#define TILE3(Ac, Bc, DOSTAGE) do { \
    const char* _ac = (Ac); const char* _bc = (Bc); \
    DOSTAGE; \
    { bf16x8 b0 = RD8(_bc, bRow +    0 + kc0); bf16x8 b1 = RD8(_bc, bRow + 2048 + kc0); \
      bf16x8 b2 = RD8(_bc, bRow + 4096 + kc0); bf16x8 b3 = RD8(_bc, bRow + 6144 + kc0); \
      bf16x8 a0 = RD8(_ac, aRow +     0 + kc0); bf16x8 a1 = RD8(_ac, aRow +  2048 + kc0); \
      bf16x8 a2 = RD8(_ac, aRow +  4096 + kc0); bf16x8 a3 = RD8(_ac, aRow +  6144 + kc0); \
      bf16x8 a4 = RD8(_ac, aRow +  8192 + kc0); bf16x8 a5 = RD8(_ac, aRow + 10240 + kc0); \
      bf16x8 a6 = RD8(_ac, aRow + 12288 + kc0); bf16x8 a7 = RD8(_ac, aRow + 14336 + kc0); \
      __builtin_amdgcn_s_setprio(1); \
      SWEEP16(0, a0, a1, a2, a3, b0, b1, b2, b3); \
      SWEEP16(4, a4, a5, a6, a7, b0, b1, b2, b3); \
      __builtin_amdgcn_s_setprio(0); } \
    { bf16x8 b0 = RD8(_bc, bRow +    0 + kc1); bf16x8 b1 = RD8(_bc, bRow + 2048 + kc1); \
      bf16x8 b2 = RD8(_bc, bRow + 4096 + kc1); bf16x8 b3 = RD8(_bc, bRow + 6144 + kc1); \
      bf16x8 a0 = RD8(_ac, aRow +     0 + kc1); bf16x8 a1 = RD8(_ac, aRow +  2048 + kc1); \
      bf16x8 a2 = RD8(_ac, aRow +  4096 + kc1); bf16x8 a3 = RD8(_ac, aRow +  6144 + kc1); \
      bf16x8 a4 = RD8(_ac, aRow +  8192 + kc1); bf16x8 a5 = RD8(_ac, aRow + 10240 + kc1); \
      bf16x8 a6 = RD8(_ac, aRow + 12288 + kc1); bf16x8 a7 = RD8(_ac, aRow + 14336 + kc1); \
      __builtin_amdgcn_s_setprio(1); \
      SWEEP16(0, a0, a1, a2, a3, b0, b1, b2, b3); \
      SWEEP16(4, a4, a5, a6, a7, b0, b1, b2, b3); \
      __builtin_amdgcn_s_setprio(0); } \
    VMW0; \
    __builtin_amdgcn_s_barrier(); \
  } while (0)

__global__ __launch_bounds__(512, 2) void gemm256_kernel(
    const __bf16* __restrict__ Xb, const __bf16* __restrict__ W,
    const float* __restrict__ bias, float* __restrict__ C,
    int M, int N, int K)
{
    __shared__ __align__(16) char smem[131072];

    const int t = threadIdx.x, wid = t >> 6, lane = t & 63;
    const int wr = wid >> 2, wc = wid & 3;
    const int l15 = lane & 15, l7 = lane & 7, lk = lane >> 4;

    const int nwg = gridDim.x;
    int bid = blockIdx.x;
    if ((nwg & 7) == 0) bid = (bid & 7) * (nwg >> 3) + (bid >> 3);
    const int ntn = N >> 8;
    const int m0 = (bid / ntn) << 8, n0 = (bid % ntn) << 8;

    const int sr = t >> 3;
    const int sc = (t & 7) ^ (sr & 7);
    const __bf16* pA0  = Xb + (long)(m0 +       sr) * K + sc * 8;
    const __bf16* pA0b = Xb + (long)(m0 +  64 + sr) * K + sc * 8;
    const __bf16* pA1  = Xb + (long)(m0 + 128 + sr) * K + sc * 8;
    const __bf16* pA1b = Xb + (long)(m0 + 192 + sr) * K + sc * 8;
    const __bf16* pB0  = W  + (long)(n0 +       sr) * K + sc * 8;
    const __bf16* pB0b = W  + (long)(n0 +  64 + sr) * K + sc * 8;
    const __bf16* pB1  = W  + (long)(n0 + 128 + sr) * K + sc * 8;
    const __bf16* pB1b = W  + (long)(n0 + 192 + sr) * K + sc * 8;

    const int wb = wid * 1024;
    const int aRow = (wr * 128 + l15) * 128;
    const int bRow = (wc * 64  + l15) * 128;
    const int kc0  = ((lk    ) ^ l7) << 4;
    const int kc1  = ((lk + 4) ^ l7) << 4;

    char* const bA0 = smem;
    char* const bB0 = smem + 32768;
    char* const bA1 = smem + 65536;
    char* const bB1 = smem + 98304;

    f32x4 acc[8][4] = {};
    const int nkt = K >> 6;

    STAGE_ALL(bA0, bB0);
    ADVP(nkt > 1 ? 64 : 0);
    VMW0;
    __builtin_amdgcn_s_barrier();

    for (int kt = 0; kt < nkt; kt += 2) {
        const long adv1 = (kt + 2 < nkt) ? 64 : 0;
        const long adv2 = (kt + 3 < nkt) ? 64 : 0;
        TILE3(bA0, bB0, { STAGE_ALL(bA1, bB1); ADVP(adv1); });
        TILE3(bA1, bB1, { STAGE_ALL(bA0, bB0); ADVP(adv2); });
    }

    #pragma unroll
    for (int nj = 0; nj < 4; ++nj) {
        const int col = n0 + wc * 64 + nj * 16 + l15;
        const float bv = bias[col];
        #pragma unroll
        for (int mi = 0; mi < 8; ++mi) {
            const long row = (long)m0 + wr * 128 + mi * 16 + (lane >> 4) * 4;
            float* Cp = C + row * N + col;
            Cp[0]       = acc[mi][nj][0] + bv;
            Cp[(long)N] = acc[mi][nj][1] + bv;
            Cp[2L * N]  = acc[mi][nj][2] + bv;
            Cp[3L * N]  = acc[mi][nj][3] + bv;
        }
    }
}

// ---------------------------------------------------------------------------
// Last-resort fallback: on-the-fly dequant+LoRA fp32 GEMM (no ws).
// ---------------------------------------------------------------------------
__global__ __launch_bounds__(256) void fallback_gemm(
    const float* __restrict__ X, const int* __restrict__ q,
    const float* __restrict__ scales, const float* __restrict__ bias,
    const float* __restrict__ lA, const float* __restrict__ lB,
    float* __restrict__ C, int M, int N, int K)
{
    __shared__ float Xs[64][17];
    __shared__ float Ws[64][17];
    __shared__ float At[LORA_RANK][16];
    __shared__ float Bt[64][LORA_RANK];

    const int ntn = N >> 6;
    const int m0 = (blockIdx.x / ntn) << 6, n0 = (blockIdx.x % ntn) << 6;
    const int t = threadIdx.x;

    for (int j = t; j < 64 * LORA_RANK; j += 256)
        Bt[j >> 4][j & 15] = lB[(long)(n0 + (j >> 4)) * LORA_RANK + (j & 15)] * SCALING;

    const int tr = (t & 15) * 4, tc = (t >> 4) * 4;
    float acc[4][4] = {};

    for (int k0 = 0; k0 < K; k0 += 16) {
        __syncthreads();
        for (int j = t; j < 1024; j += 256)
            Xs[j >> 4][j & 15] = X[(long)(m0 + (j >> 4)) * K + k0 + (j & 15)];
        At[t >> 4][t & 15] = lA[(long)(t >> 4) * K + k0 + (t & 15)];
        __syncthreads();
        for (int j = t; j < 1024; j += 256) {
            int o = j >> 4, kk = j & 15;
            float v = (float)q[(long)(n0 + o) * K + k0 + kk] * scales[n0 + o];
            #pragma unroll
            for (int r = 0; r < LORA_RANK; ++r) v += Bt[o][r] * At[r][kk];
            Ws[o][kk] = v;
        }
        __syncthreads();
        #pragma unroll 4
        for (int kk = 0; kk < 16; ++kk)
            #pragma unroll
            for (int i = 0; i < 4; ++i)
                #pragma unroll
                for (int j = 0; j < 4; ++j)
                    acc[i][j] += Xs[tr + i][kk] * Ws[tc + j][kk];
    }
    __syncthreads();
    #pragma unroll
    for (int i = 0; i < 4; ++i)
        #pragma unroll
        for (int j = 0; j < 4; ++j)
            C[(long)(m0 + tr + i) * N + n0 + tc + j] = acc[i][j] + bias[n0 + tc + j];
}

// ---------------------------------------------------------------------------
extern "C" void kernel_launch(void* const* d_in, const int* in_sizes, int n_in,
                              void* d_out, int out_size, void* d_ws, size_t ws_size,
                              hipStream_t stream)
{
    const float* x      = (const float*)d_in[0];
    const int*   qw     = (const int*)d_in[1];
    const float* scales = (const float*)d_in[2];
    const float* bias   = (const float*)d_in[3];
    const float* lA     = (const float*)d_in[4];
    const float* lB     = (const float*)d_in[5];
    float*       out    = (float*)d_out;

    const int K = in_sizes[4] / LORA_RANK;   // 4096
    const int N = in_sizes[2];               // 4096
    const int M = in_sizes[0] / K;           // 8192

    // ---- int8 path (256x128 blocks, BK=128; L kept as bf16 in ws) ----
    const size_t i8need = (size_t)N * K + (size_t)M * K + (size_t)(M + N) * 4
                        + (size_t)N * K * 2 + 256;
    const bool i8_ok = (K == 4096) && (M % 256) == 0 && (N % 128) == 0 &&
                       ws_size >= i8need;
    // ---- bf16 path ----
    const size_t wbytes = (size_t)N * K * sizeof(__bf16);
    const size_t xbytes = (size_t)M * K * sizeof(__bf16);
    const bool big_ok = (M % 256) == 0 && (N % 256) == 0 && (K % 256) == 0 &&
                        ((K >> 6) % 2) == 0 && ws_size >= wbytes + xbytes;

    if (i8_ok) {
        signed char* W8  = (signed char*)d_ws;
        signed char* X8  = W8 + (size_t)N * K;
        float*       sxm = (float*)(X8 + (size_t)M * K);
        float*       sn  = sxm + M;
        __bf16*      L   = (__bf16*)(sn + N);

        dim3 g1(K / 256, N / 64);
        lora_mat_kernel<<<g1, 256, 0, stream>>>(lA, lB, L, N, K);
        quant_w_kernel<<<N, 256, 0, stream>>>(qw, scales, L, W8, sn, K);
        quant_x_kernel<<<M, 256, 0, stream>>>(x, X8, sxm, K);
        const int nwg = (M / 256) * (N / 128);
        gemm_i8_kernel<<<nwg, 512, 0, stream>>>(X8, W8, sxm, sn, bias, out, M, N, K);
    } else if (big_ok) {
        __bf16* W  = (__bf16*)d_ws;
        __bf16* Xb = (__bf16*)((char*)d_ws + wbytes);
        dim3 g1(K / 256, N / 64);
        fold_weight_kernel<<<g1, 256, 0, stream>>>(qw, scales, lA, lB, W, N, K);
        cvt_x_kernel<<<2048, 256, 0, stream>>>(x, Xb, (long)M * K);
        const int nwg = (M / 256) * (N / 256);
        gemm256_kernel<<<nwg, 512, 0, stream>>>(Xb, W, bias, out, M, N, K);
    } else {
        fallback_gemm<<<(M / 64) * (N / 64), 256, 0, stream>>>(
            x, qw, scales, bias, lA, lB, out, M, N, K);
    }
}

// Round 13
// 219.846 us; speedup vs baseline: 1.0419x; 1.0419x over previous
//
#include <hip/hip_runtime.h>

#define LORA_RANK 16
#define SCALING 2.0f

using bf16x8 = __attribute__((ext_vector_type(8))) __bf16;
using bf16x4 = __attribute__((ext_vector_type(4))) __bf16;
using f32x4  = __attribute__((ext_vector_type(4))) float;
using i32x4  = __attribute__((ext_vector_type(4))) int;

#define GLB(p) ((const __attribute__((address_space(1))) void*)(p))
#define LDS(p) ((__attribute__((address_space(3))) void*)(p))

// ---------------------------------------------------------------------------
// L[o][i] = SCALING * sum_r lB[o][r]*lA[r][i]  -> bf16 into d_ws scratch.
// ---------------------------------------------------------------------------
__global__ __launch_bounds__(256) void lora_mat_kernel(
    const float* __restrict__ lA, const float* __restrict__ lB,
    __bf16* __restrict__ L, int N, int K)
{
    const int i0 = blockIdx.x * 256;
    const int o0 = blockIdx.y * 64;
    const int t  = threadIdx.x;

    __shared__ float As[LORA_RANK][256];
    __shared__ float Bs[64][LORA_RANK];

    #pragma unroll
    for (int j = 0; j < 16; ++j) {
        int idx = t + j * 256;
        int r = idx >> 8, c = idx & 255;
        As[r][c] = lA[(long)r * K + i0 + c];
    }
    #pragma unroll
    for (int j = 0; j < 4; ++j) {
        int idx = t + j * 256;
        int o = idx >> 4, r = idx & 15;
        Bs[o][r] = lB[(long)(o0 + o) * LORA_RANK + r] * SCALING;
    }
    __syncthreads();

    const int ol = t & 63;
    const int iq = t >> 6;
    const int o  = o0 + ol;

    float bb[LORA_RANK];
    #pragma unroll
    for (int r = 0; r < LORA_RANK; ++r) bb[r] = Bs[ol][r];

    __bf16* lrow = L + (long)o * K + i0 + iq * 64;
    #pragma unroll
    for (int c = 0; c < 16; ++c) {
        const int ib = iq * 64 + c * 4;
        f32x4 v = {0.f, 0.f, 0.f, 0.f};
        #pragma unroll
        for (int r = 0; r < LORA_RANK; ++r) {
            v[0] += bb[r] * As[r][ib + 0];
            v[1] += bb[r] * As[r][ib + 1];
            v[2] += bb[r] * As[r][ib + 2];
            v[3] += bb[r] * As[r][ib + 3];
        }
        bf16x4 wv;
        wv[0] = (__bf16)v[0]; wv[1] = (__bf16)v[1];
        wv[2] = (__bf16)v[2]; wv[3] = (__bf16)v[3];
        *(bf16x4*)(lrow + c * 4) = wv;
    }
}

// ---------------------------------------------------------------------------
// Per-output-row: W' = q*s + L; s' = rowmax/127; W8 = round(W'/s').  K==4096.
// ---------------------------------------------------------------------------
__global__ __launch_bounds__(256) void quant_w_kernel(
    const int* __restrict__ q, const float* __restrict__ scales,
    const __bf16* __restrict__ L, signed char* __restrict__ W8,
    float* __restrict__ sn, int K)
{
    const int o = blockIdx.x, t = threadIdx.x;
    __shared__ float buf[4096];
    __shared__ float red[256];

    const int4*   qr = (const int4*)(q + (long)o * K);
    const bf16x4* Lr = (const bf16x4*)(L + (long)o * K);
    const float   s  = scales[o];

    float mx = 0.f;
    #pragma unroll
    for (int j = 0; j < 4; ++j) {
        int c = t + j * 256;
        int4   qv = qr[c];
        bf16x4 lv = Lr[c];
        f32x4 w;
        w[0] = (float)qv.x * s + (float)lv[0];
        w[1] = (float)qv.y * s + (float)lv[1];
        w[2] = (float)qv.z * s + (float)lv[2];
        w[3] = (float)qv.w * s + (float)lv[3];
        *(f32x4*)&buf[c * 4] = w;
        mx = fmaxf(mx, fmaxf(fmaxf(fabsf(w[0]), fabsf(w[1])),
                             fmaxf(fabsf(w[2]), fabsf(w[3]))));
    }
    red[t] = mx;
    __syncthreads();
    for (int s2 = 128; s2 > 0; s2 >>= 1) {
        if (t < s2) red[t] = fmaxf(red[t], red[t + s2]);
        __syncthreads();
    }
    const float gmax = fmaxf(red[0], 1e-30f);
    const float winv = 127.0f / gmax;

    int* wrow = (int*)(W8 + (long)o * K);
    #pragma unroll
    for (int j = 0; j < 4; ++j) {
        int c = t + j * 256;
        f32x4 w = *(const f32x4*)&buf[c * 4];
        int c0 = (int)rintf(fminf(fmaxf(w[0] * winv, -127.f), 127.f));
        int c1 = (int)rintf(fminf(fmaxf(w[1] * winv, -127.f), 127.f));
        int c2 = (int)rintf(fminf(fmaxf(w[2] * winv, -127.f), 127.f));
        int c3 = (int)rintf(fminf(fmaxf(w[3] * winv, -127.f), 127.f));
        wrow[c] = (c0 & 255) | ((c1 & 255) << 8) | ((c2 & 255) << 16) | (c3 << 24);
    }
    if (t == 0) sn[o] = gmax / 127.0f;
}

// ---------------------------------------------------------------------------
// Per-X-row: sx = rowmax|x|/127; X8 = round(x/sx).  K==4096.
// ---------------------------------------------------------------------------
__global__ __launch_bounds__(256) void quant_x_kernel(
    const float* __restrict__ X, signed char* __restrict__ X8,
    float* __restrict__ sxm, int K)
{
    const int m = blockIdx.x, t = threadIdx.x;
    __shared__ float red[256];

    const f32x4* xr = (const f32x4*)(X + (long)m * K);
    f32x4 v[4];
    float mx = 0.f;
    #pragma unroll
    for (int j = 0; j < 4; ++j) {
        v[j] = xr[t + j * 256];
        mx = fmaxf(mx, fmaxf(fmaxf(fabsf(v[j][0]), fabsf(v[j][1])),
                             fmaxf(fabsf(v[j][2]), fabsf(v[j][3]))));
    }
    red[t] = mx;
    __syncthreads();
    for (int s2 = 128; s2 > 0; s2 >>= 1) {
        if (t < s2) red[t] = fmaxf(red[t], red[t + s2]);
        __syncthreads();
    }
    const float gmax = fmaxf(red[0], 1e-30f);
    const float xinv = 127.0f / gmax;

    int* xrow = (int*)(X8 + (long)m * K);
    #pragma unroll
    for (int j = 0; j < 4; ++j) {
        int c0 = (int)rintf(fminf(fmaxf(v[j][0] * xinv, -127.f), 127.f));
        int c1 = (int)rintf(fminf(fmaxf(v[j][1] * xinv, -127.f), 127.f));
        int c2 = (int)rintf(fminf(fmaxf(v[j][2] * xinv, -127.f), 127.f));
        int c3 = (int)rintf(fminf(fmaxf(v[j][3] * xinv, -127.f), 127.f));
        xrow[t + j * 256] = (c0 & 255) | ((c1 & 255) << 8) | ((c2 & 255) << 16) | (c3 << 24);
    }
    if (t == 0) sxm[m] = gmax / 127.0f;
}

// ---------------------------------------------------------------------------
// INT8 GEMM: 256x256 tile, BK=128, 128B rows + 8-chunk XOR swizzle (verified
// conflict-free). Register slice pipeline at FULL tile: two fragment sets;
// {READF(slice s+1) || MFMAS(slice s)} with no wait between; one
// lgkm+vmcnt+barrier per K-tile at the buffer swap.
// ---------------------------------------------------------------------------
#define VMW0  asm volatile("s_waitcnt vmcnt(0)" ::: "memory")
#define VMW8  asm volatile("s_waitcnt vmcnt(8)" ::: "memory")
#define LGKM0 asm volatile("s_waitcnt lgkmcnt(0)" ::: "memory")

#define RD4(base, off) (*(const i32x4*)((base) + (off)))

#define MFI(mi, nj, A, B) \
    acc[mi][nj] = __builtin_amdgcn_mfma_i32_16x16x64_i8(A, B, acc[mi][nj], 0, 0, 0)

#define DECLF(p) i32x4 p##a0, p##a1, p##a2, p##a3, p##a4, p##a5, p##a6, p##a7, \
                       p##b0, p##b1, p##b2, p##b3

#define READF12(p, ac, bc, kc) do { \
    p##b0 = RD4(bc, bRow +    0 + (kc)); \
    p##b1 = RD4(bc, bRow + 2048 + (kc)); \
    p##b2 = RD4(bc, bRow + 4096 + (kc)); \
    p##b3 = RD4(bc, bRow + 6144 + (kc)); \
    p##a0 = RD4(ac, aRow +     0 + (kc)); \
    p##a1 = RD4(ac, aRow +  2048 + (kc)); \
    p##a2 = RD4(ac, aRow +  4096 + (kc)); \
    p##a3 = RD4(ac, aRow +  6144 + (kc)); \
    p##a4 = RD4(ac, aRow +  8192 + (kc)); \
    p##a5 = RD4(ac, aRow + 10240 + (kc)); \
    p##a6 = RD4(ac, aRow + 12288 + (kc)); \
    p##a7 = RD4(ac, aRow + 14336 + (kc)); } while (0)

#define MFMAS32(p) do { \
    __builtin_amdgcn_s_setprio(1); \
    MFI(0,0,p##a0,p##b0); MFI(1,0,p##a1,p##b0); MFI(2,0,p##a2,p##b0); MFI(3,0,p##a3,p##b0); \
    MFI(4,0,p##a4,p##b0); MFI(5,0,p##a5,p##b0); MFI(6,0,p##a6,p##b0); MFI(7,0,p##a7,p##b0); \
    MFI(0,1,p##a0,p##b1); MFI(1,1,p##a1,p##b1); MFI(2,1,p##a2,p##b1); MFI(3,1,p##a3,p##b1); \
    MFI(4,1,p##a4,p##b1); MFI(5,1,p##a5,p##b1); MFI(6,1,p##a6,p##b1); MFI(7,1,p##a7,p##b1); \
    MFI(0,2,p##a0,p##b2); MFI(1,2,p##a1,p##b2); MFI(2,2,p##a2,p##b2); MFI(3,2,p##a3,p##b2); \
    MFI(4,2,p##a4,p##b2); MFI(5,2,p##a5,p##b2); MFI(6,2,p##a6,p##b2); MFI(7,2,p##a7,p##b2); \
    MFI(0,3,p##a0,p##b3); MFI(1,3,p##a1,p##b3); MFI(2,3,p##a2,p##b3); MFI(3,3,p##a3,p##b3); \
    MFI(4,3,p##a4,p##b3); MFI(5,3,p##a5,p##b3); MFI(6,3,p##a6,p##b3); MFI(7,3,p##a7,p##b3); \
    __builtin_amdgcn_s_setprio(0); } while (0)

// stage 256x128B A + 256x128B B (64KB) = 8 DMA / thread
#define STAGE8(dA, dB) do { \
    __builtin_amdgcn_global_load_lds(GLB(pB),          LDS((dB) + wb),         16, 0, 0); \
    __builtin_amdgcn_global_load_lds(GLB(pB + rk),     LDS((dB) + wb +  8192), 16, 0, 0); \
    __builtin_amdgcn_global_load_lds(GLB(pB + 2 * rk), LDS((dB) + wb + 16384), 16, 0, 0); \
    __builtin_amdgcn_global_load_lds(GLB(pB + 3 * rk), LDS((dB) + wb + 24576), 16, 0, 0); \
    __builtin_amdgcn_global_load_lds(GLB(pA),          LDS((dA) + wb),         16, 0, 0); \
    __builtin_amdgcn_global_load_lds(GLB(pA + rk),     LDS((dA) + wb +  8192), 16, 0, 0); \
    __builtin_amdgcn_global_load_lds(GLB(pA + 2 * rk), LDS((dA) + wb + 16384), 16, 0, 0); \
    __builtin_amdgcn_global_load_lds(GLB(pA + 3 * rk), LDS((dA) + wb + 24576), 16, 0, 0); } while (0)

#define ADVP8(a) do { pA += (a); pB += (a); } while (0)

__global__ __launch_bounds__(512, 2) void gemm_i8_kernel(
    const signed char* __restrict__ X8, const signed char* __restrict__ W8,
    const float* __restrict__ sxm, const float* __restrict__ sn,
    const float* __restrict__ bias, float* __restrict__ C,
    int M, int N, int K)
{
    // buf0 A [0,32K) B [32K,64K) | buf1 A [64K,96K) B [96K,128K)
    __shared__ __align__(16) char smem[131072];

    const int t = threadIdx.x, wid = t >> 6, lane = t & 63;
    const int wr = wid >> 2, wc = wid & 3;
    const int l15 = lane & 15, l7 = lane & 7, lk = lane >> 4;

    const int nwg = gridDim.x;
    int bid = blockIdx.x;
    if ((nwg & 7) == 0) bid = (bid & 7) * (nwg >> 3) + (bid >> 3);
    const int ntn = N >> 8;
    const int m0 = (bid / ntn) << 8, n0 = (bid % ntn) << 8;

    // staging: thread t sources row (t>>3)(+64k), chunk (t&7)^((t>>3)&7)
    const int sr = t >> 3;
    const int ch = (t & 7) ^ (sr & 7);
    const long rk = 64L * K;
    const signed char* pA = X8 + (long)(m0 + sr) * K + ch * 16;
    const signed char* pB = W8 + (long)(n0 + sr) * K + ch * 16;

    const int wb = wid * 1024;                     // wave-uniform stage base

    // fragment reads: row base+l15 (+16*mi), k-chunk (lk + 4*ks) ^ (row&7)
    const int aRow = (wr * 128 + l15) * 128;
    const int bRow = (wc * 64  + l15) * 128;
    const int kc0  = ((lk    ) ^ l7) << 4;
    const int kc1  = ((lk + 4) ^ l7) << 4;

    char* const bA0 = smem;
    char* const bB0 = smem + 32768;
    char* const bA1 = smem + 65536;
    char* const bB1 = smem + 98304;

    i32x4 acc[8][4] = {};

    const int nkt = K >> 7;                        // BK = 128 (nkt even)

    // prologue: stage tiles 0 and 1, wait tile 0, read its slice 0
    STAGE8(bA0, bB0);
    ADVP8(nkt > 1 ? 128 : 0);
    STAGE8(bA1, bB1);
    ADVP8(nkt > 2 ? 128 : 0);
    VMW8;                                          // tile0's 8 DMAs done
    __builtin_amdgcn_s_barrier();

    DECLF(x);
    DECLF(y);
    READF12(x, bA0, bB0, kc0);

    for (int kt = 0; kt < nkt; kt += 2) {
        // ---- tile kt (buf0) ----
        READF12(y, bA0, bB0, kc1);                 // slice1 reads, no wait
        MFMAS32(x);                                // slice0 MFMAs overlap
        LGKM0;                                     // buf0 reads complete
        VMW0;                                      // buf1 staging complete
        __builtin_amdgcn_s_barrier();
        STAGE8(bA0, bB0);                          // stage kt+2 over buf0
        ADVP8((kt + 3 < nkt) ? 128 : 0);
        READF12(x, bA1, bB1, kc0);                 // next tile slice0
        MFMAS32(y);                                // slice1 MFMAs overlap
        // ---- tile kt+1 (buf1) ----
        READF12(y, bA1, bB1, kc1);
        MFMAS32(x);
        LGKM0;
        VMW0;                                      // buf0 staging complete
        __builtin_amdgcn_s_barrier();
        STAGE8(bA1, bB1);                          // stage kt+3 over buf1
        ADVP8((kt + 4 < nkt) ? 128 : 0);
        READF12(x, bA0, bB0, kc0);
        MFMAS32(y);
    }

    // epilogue: col = lane&15 (+nj*16), row = (lane>>4)*4 + e (+mi*16)
    #pragma unroll
    for (int nj = 0; nj < 4; ++nj) {
        const int col = n0 + wc * 64 + nj * 16 + l15;
        const float scol = sn[col];
        const float bv   = bias[col];
        #pragma unroll
        for (int mi = 0; mi < 8; ++mi) {
            const long rowb = (long)m0 + wr * 128 + mi * 16 + (lane >> 4) * 4;
            const f32x4 sx4 = *(const f32x4*)(sxm + rowb);
            float* Cp = C + rowb * N + col;
            Cp[0]       = (float)acc[mi][nj][0] * (sx4[0] * scol) + bv;
            Cp[(long)N] = (float)acc[mi][nj][1] * (sx4[1] * scol) + bv;
            Cp[2L * N]  = (float)acc[mi][nj][2] * (sx4[2] * scol) + bv;
            Cp[3L * N]  = (float)acc[mi][nj][3] * (sx4[3] * scol) + bv;
        }
    }
}

// ---------------------------------------------------------------------------
// bf16 fallback path for unexpected shapes.
// ---------------------------------------------------------------------------
__global__ __launch_bounds__(256) void fold_weight_kernel(
    const int* __restrict__ q, const float* __restrict__ scales,
    const float* __restrict__ lA, const float* __restrict__ lB,
    __bf16* __restrict__ W, int N, int K)
{
    const int i0 = blockIdx.x * 256;
    const int o0 = blockIdx.y * 64;
    const int t  = threadIdx.x;

    __shared__ float As[LORA_RANK][256];
    __shared__ float Bs[64][LORA_RANK];

    #pragma unroll
    for (int j = 0; j < 16; ++j) {
        int idx = t + j * 256;
        As[idx >> 8][idx & 255] = lA[(long)(idx >> 8) * K + i0 + (idx & 255)];
    }
    #pragma unroll
    for (int j = 0; j < 4; ++j) {
        int idx = t + j * 256;
        Bs[idx >> 4][idx & 15] = lB[(long)(o0 + (idx >> 4)) * LORA_RANK + (idx & 15)] * SCALING;
    }
    __syncthreads();

    const int ol = t & 63, iq = t >> 6, o = o0 + ol;
    const float sc = scales[o];
    float bb[LORA_RANK];
    #pragma unroll
    for (int r = 0; r < LORA_RANK; ++r) bb[r] = Bs[ol][r];

    const int* qrow = q + (long)o * K + i0 + iq * 64;
    __bf16*    wrow = W + (long)o * K + i0 + iq * 64;
    #pragma unroll
    for (int c = 0; c < 16; ++c) {
        int4 q4 = *(const int4*)(qrow + c * 4);
        float v[4] = {(float)q4.x * sc, (float)q4.y * sc, (float)q4.z * sc, (float)q4.w * sc};
        const int ib = iq * 64 + c * 4;
        #pragma unroll
        for (int r = 0; r < LORA_RANK; ++r) {
            v[0] += bb[r] * As[r][ib + 0]; v[1] += bb[r] * As[r][ib + 1];
            v[2] += bb[r] * As[r][ib + 2]; v[3] += bb[r] * As[r][ib + 3];
        }
        bf16x4 wv; wv[0] = (__bf16)v[0]; wv[1] = (__bf16)v[1];
        wv[2] = (__bf16)v[2]; wv[3] = (__bf16)v[3];
        *(bf16x4*)(wrow + c * 4) = wv;
    }
}

__global__ __launch_bounds__(256) void cvt_x_kernel(
    const float* __restrict__ X, __bf16* __restrict__ Xb, long n)
{
    const long stride = (long)gridDim.x * 256 * 8;
    for (long i = ((long)blockIdx.x * 256 + threadIdx.x) * 8; i < n; i += stride) {
        f32x4 a = *(const f32x4*)(X + i);
        f32x4 b = *(const f32x4*)(X + i + 4);
        bf16x8 v;
        #pragma unroll
        for (int j = 0; j < 4; ++j) { v[j] = (__bf16)a[j]; v[j + 4] = (__bf16)b[j]; }
        *(bf16x8*)(Xb + i) = v;
    }
}

#define RD8(base, off) (*(const bf16x8*)((base) + (off)))
#define MF(mi, nj, A, B) \
    acc[mi][nj] = __builtin_amdgcn_mfma_f32_16x16x32_bf16(A, B, acc[mi][nj], 0, 0, 0)
#define SWEEP16(qb, A0, A1, A2, A3, B0, B1, B2, B3) \
    MF((qb)+0,0,A0,B0); MF((qb)+1,0,A1,B0); MF((qb)+2,0,A2,B0); MF((qb)+3,0,A3,B0); \
    MF((qb)+0,1,A0,B1); MF((qb)+1,1,A1,B1); MF((qb)+2,1,A2,B1); MF((qb)+3,1,A3,B1); \
    MF((qb)+0,2,A0,B2); MF((qb)+1,2,A1,B2); MF((qb)+2,2,A2,B2); MF((qb)+3,2,A3,B2); \
    MF((qb)+0,3,A0,B3); MF((qb)+1,3,A1,B3); MF((qb)+2,3,A2,B3); MF((qb)+3,3,A3,B3);
#define STAGE_ALL(dA, dB) do { \
    __builtin_amdgcn_global_load_lds(GLB(pB0),  LDS((dB) + wb),         16, 0, 0); \
    __builtin_amdgcn_global_load_lds(GLB(pB0b), LDS((dB) + wb +  8192), 16, 0, 0); \
    __builtin_amdgcn_global_load_lds(GLB(pB1),  LDS((dB) + wb + 16384), 16, 0, 0); \
    __builtin_amdgcn_global_load_lds(GLB(pB1b), LDS((dB) + wb + 24576), 16, 0, 0); \
    __builtin_amdgcn_global_load_lds(GLB(pA0),  LDS((dA) + wb),         16, 0, 0); \
    __builtin_amdgcn_global_load_lds(GLB(pA0b), LDS((dA) + wb +  8192), 16, 0, 0); \
    __builtin_amdgcn_global_load_lds(GLB(pA1),  LDS((dA) + wb + 16384), 16, 0, 0); \
    __builtin_amdgcn_global_load_lds(GLB(pA1b), LDS((dA) + wb + 24576), 16, 0, 0); } while (0)
#define ADVP(a) do { pA0 += (a); pA0b += (a); pA1 += (a); pA1b += (a); \
                     pB0 += (a); pB0b += (a); pB1 += (a); pB1b += (a); } while (0)
#define TILE3(Ac, Bc, DOSTAGE) do { \
    const char* _ac = (Ac); const char* _bc = (Bc); \
    DOSTAGE; \
    { bf16x8 b0 = RD8(_bc, bRow +    0 + kc0); bf16x8 b1 = RD8(_bc, bRow + 2048 + kc0); \
      bf16x8 b2 = RD8(_bc, bRow + 4096 + kc0); bf16x8 b3 = RD8(_bc, bRow + 6144 + kc0); \
      bf16x8 a0 = RD8(_ac, aRow +     0 + kc0); bf16x8 a1 = RD8(_ac, aRow +  2048 + kc0); \
      bf16x8 a2 = RD8(_ac, aRow +  4096 + kc0); bf16x8 a3 = RD8(_ac, aRow +  6144 + kc0); \
      bf16x8 a4 = RD8(_ac, aRow +  8192 + kc0); bf16x8 a5 = RD8(_ac, aRow + 10240 + kc0); \
      bf16x8 a6 = RD8(_ac, aRow + 12288 + kc0); bf16x8 a7 = RD8(_ac, aRow + 14336 + kc0); \
      __builtin_amdgcn_s_setprio(1); \
      SWEEP16(0, a0, a1, a2, a3, b0, b1, b2, b3); \
      SWEEP16(4, a4, a5, a6, a7, b0, b1, b2, b3); \
      __builtin_amdgcn_s_setprio(0); } \
    { bf16x8 b0 = RD8(_bc, bRow +    0 + kc1); bf16x8 b1 = RD8(_bc, bRow + 2048 + kc1); \
      bf16x8 b2 = RD8(_bc, bRow + 4096 + kc1); bf16x8 b3 = RD8(_bc, bRow + 6144 + kc1); \
      bf16x8 a0 = RD8(_ac, aRow +     0 + kc1); bf16x8 a1 = RD8(_ac, aRow +  2048 + kc1); \
      bf16x8 a2 = RD8(_ac, aRow +  4096 + kc1); bf16x8 a3 = RD8(_ac, aRow +  6144 + kc1); \
      bf16x8 a4 = RD8(_ac, aRow +  8192 + kc1); bf16x8 a5 = RD8(_ac, aRow + 10240 + kc1); \
      bf16x8 a6 = RD8(_ac, aRow + 12288 + kc1); bf16x8 a7 = RD8(_ac, aRow + 14336 + kc1); \
      __builtin_amdgcn_s_setprio(1); \
      SWEEP16(0, a0, a1, a2, a3, b0, b1, b2, b3); \
      SWEEP16(4, a4, a5, a6, a7, b0, b1, b2, b3); \
      __builtin_amdgcn_s_setprio(0); } \
    VMW0; \
    __builtin_amdgcn_s_barrier(); \
  } while (0)

__global__ __launch_bounds__(512, 2) void gemm256_kernel(
    const __bf16* __restrict__ Xb, const __bf16* __restrict__ W,
    const float* __restrict__ bias, float* __restrict__ C,
    int M, int N, int K)
{
    __shared__ __align__(16) char smem[131072];

    const int t = threadIdx.x, wid = t >> 6, lane = t & 63;
    const int wr = wid >> 2, wc = wid & 3;
    const int l15 = lane & 15, l7 = lane & 7, lk = lane >> 4;

    const int nwg = gridDim.x;
    int bid = blockIdx.x;
    if ((nwg & 7) == 0) bid = (bid & 7) * (nwg >> 3) + (bid >> 3);
    const int ntn = N >> 8;
    const int m0 = (bid / ntn) << 8, n0 = (bid % ntn) << 8;

    const int sr = t >> 3;
    const int sc = (t & 7) ^ (sr & 7);
    const __bf16* pA0  = Xb + (long)(m0 +       sr) * K + sc * 8;
    const __bf16* pA0b = Xb + (long)(m0 +  64 + sr) * K + sc * 8;
    const __bf16* pA1  = Xb + (long)(m0 + 128 + sr) * K + sc * 8;
    const __bf16* pA1b = Xb + (long)(m0 + 192 + sr) * K + sc * 8;
    const __bf16* pB0  = W  + (long)(n0 +       sr) * K + sc * 8;
    const __bf16* pB0b = W  + (long)(n0 +  64 + sr) * K + sc * 8;
    const __bf16* pB1  = W  + (long)(n0 + 128 + sr) * K + sc * 8;
    const __bf16* pB1b = W  + (long)(n0 + 192 + sr) * K + sc * 8;

    const int wb = wid * 1024;
    const int aRow = (wr * 128 + l15) * 128;
    const int bRow = (wc * 64  + l15) * 128;
    const int kc0  = ((lk    ) ^ l7) << 4;
    const int kc1  = ((lk + 4) ^ l7) << 4;

    char* const bA0 = smem;
    char* const bB0 = smem + 32768;
    char* const bA1 = smem + 65536;
    char* const bB1 = smem + 98304;

    f32x4 acc[8][4] = {};
    const int nkt = K >> 6;

    STAGE_ALL(bA0, bB0);
    ADVP(nkt > 1 ? 64 : 0);
    VMW0;
    __builtin_amdgcn_s_barrier();

    for (int kt = 0; kt < nkt; kt += 2) {
        const long adv1 = (kt + 2 < nkt) ? 64 : 0;
        const long adv2 = (kt + 3 < nkt) ? 64 : 0;
        TILE3(bA0, bB0, { STAGE_ALL(bA1, bB1); ADVP(adv1); });
        TILE3(bA1, bB1, { STAGE_ALL(bA0, bB0); ADVP(adv2); });
    }

    #pragma unroll
    for (int nj = 0; nj < 4; ++nj) {
        const int col = n0 + wc * 64 + nj * 16 + l15;
        const float bv = bias[col];
        #pragma unroll
        for (int mi = 0; mi < 8; ++mi) {
            const long row = (long)m0 + wr * 128 + mi * 16 + (lane >> 4) * 4;
            float* Cp = C + row * N + col;
            Cp[0]       = acc[mi][nj][0] + bv;
            Cp[(long)N] = acc[mi][nj][1] + bv;
            Cp[2L * N]  = acc[mi][nj][2] + bv;
            Cp[3L * N]  = acc[mi][nj][3] + bv;
        }
    }
}

// ---------------------------------------------------------------------------
// Last-resort fallback: on-the-fly dequant+LoRA fp32 GEMM (no ws).
// ---------------------------------------------------------------------------
__global__ __launch_bounds__(256) void fallback_gemm(
    const float* __restrict__ X, const int* __restrict__ q,
    const float* __restrict__ scales, const float* __restrict__ bias,
    const float* __restrict__ lA, const float* __restrict__ lB,
    float* __restrict__ C, int M, int N, int K)
{
    __shared__ float Xs[64][17];
    __shared__ float Ws[64][17];
    __shared__ float At[LORA_RANK][16];
    __shared__ float Bt[64][LORA_RANK];

    const int ntn = N >> 6;
    const int m0 = (blockIdx.x / ntn) << 6, n0 = (blockIdx.x % ntn) << 6;
    const int t = threadIdx.x;

    for (int j = t; j < 64 * LORA_RANK; j += 256)
        Bt[j >> 4][j & 15] = lB[(long)(n0 + (j >> 4)) * LORA_RANK + (j & 15)] * SCALING;

    const int tr = (t & 15) * 4, tc = (t >> 4) * 4;
    float acc[4][4] = {};

    for (int k0 = 0; k0 < K; k0 += 16) {
        __syncthreads();
        for (int j = t; j < 1024; j += 256)
            Xs[j >> 4][j & 15] = X[(long)(m0 + (j >> 4)) * K + k0 + (j & 15)];
        At[t >> 4][t & 15] = lA[(long)(t >> 4) * K + k0 + (t & 15)];
        __syncthreads();
        for (int j = t; j < 1024; j += 256) {
            int o = j >> 4, kk = j & 15;
            float v = (float)q[(long)(n0 + o) * K + k0 + kk] * scales[n0 + o];
            #pragma unroll
            for (int r = 0; r < LORA_RANK; ++r) v += Bt[o][r] * At[r][kk];
            Ws[o][kk] = v;
        }
        __syncthreads();
        #pragma unroll 4
        for (int kk = 0; kk < 16; ++kk)
            #pragma unroll
            for (int i = 0; i < 4; ++i)
                #pragma unroll
                for (int j = 0; j < 4; ++j)
                    acc[i][j] += Xs[tr + i][kk] * Ws[tc + j][kk];
    }
    __syncthreads();
    #pragma unroll
    for (int i = 0; i < 4; ++i)
        #pragma unroll
        for (int j = 0; j < 4; ++j)
            C[(long)(m0 + tr + i) * N + n0 + tc + j] = acc[i][j] + bias[n0 + tc + j];
}

// ---------------------------------------------------------------------------
extern "C" void kernel_launch(void* const* d_in, const int* in_sizes, int n_in,
                              void* d_out, int out_size, void* d_ws, size_t ws_size,
                              hipStream_t stream)
{
    const float* x      = (const float*)d_in[0];
    const int*   qw     = (const int*)d_in[1];
    const float* scales = (const float*)d_in[2];
    const float* bias   = (const float*)d_in[3];
    const float* lA     = (const float*)d_in[4];
    const float* lB     = (const float*)d_in[5];
    float*       out    = (float*)d_out;

    const int K = in_sizes[4] / LORA_RANK;   // 4096
    const int N = in_sizes[2];               // 4096
    const int M = in_sizes[0] / K;           // 8192

    // ---- int8 path (256x256 tile, BK=128; L kept as bf16 in ws) ----
    const size_t i8need = (size_t)N * K + (size_t)M * K + (size_t)(M + N) * 4
                        + (size_t)N * K * 2 + 256;
    const bool i8_ok = (K == 4096) && (M % 256) == 0 && (N % 256) == 0 &&
                       ws_size >= i8need;
    // ---- bf16 path ----
    const size_t wbytes = (size_t)N * K * sizeof(__bf16);
    const size_t xbytes = (size_t)M * K * sizeof(__bf16);
    const bool big_ok = (M % 256) == 0 && (N % 256) == 0 && (K % 256) == 0 &&
                        ((K >> 6) % 2) == 0 && ws_size >= wbytes + xbytes;

    if (i8_ok) {
        signed char* W8  = (signed char*)d_ws;
        signed char* X8  = W8 + (size_t)N * K;
        float*       sxm = (float*)(X8 + (size_t)M * K);
        float*       sn  = sxm + M;
        __bf16*      L   = (__bf16*)(sn + N);

        dim3 g1(K / 256, N / 64);
        lora_mat_kernel<<<g1, 256, 0, stream>>>(lA, lB, L, N, K);
        quant_w_kernel<<<N, 256, 0, stream>>>(qw, scales, L, W8, sn, K);
        quant_x_kernel<<<M, 256, 0, stream>>>(x, X8, sxm, K);
        const int nwg = (M / 256) * (N / 256);
        gemm_i8_kernel<<<nwg, 512, 0, stream>>>(X8, W8, sxm, sn, bias, out, M, N, K);
    } else if (big_ok) {
        __bf16* W  = (__bf16*)d_ws;
        __bf16* Xb = (__bf16*)((char*)d_ws + wbytes);
        dim3 g1(K / 256, N / 64);
        fold_weight_kernel<<<g1, 256, 0, stream>>>(qw, scales, lA, lB, W, N, K);
        cvt_x_kernel<<<2048, 256, 0, stream>>>(x, Xb, (long)M * K);
        const int nwg = (M / 256) * (N / 256);
        gemm256_kernel<<<nwg, 512, 0, stream>>>(Xb, W, bias, out, M, N, K);
    } else {
        fallback_gemm<<<(M / 64) * (N / 64), 256, 0, stream>>>(
            x, qw, scales, bias, lA, lB, out, M, N, K);
    }
}